// Round 6
// baseline (2347.777 us; speedup 1.0000x reference)
//
#include <hip/hip_runtime.h>
#include <cstddef>
#include <cstdint>

#define B_ 512
#define T_ 2048
#define I_ 16
#define H_ 40

typedef __fp16 half_t;  // matches __builtin_amdgcn_* vector element type exactly
typedef half_t h2 __attribute__((ext_vector_type(2)));
typedef half_t h8 __attribute__((ext_vector_type(8)));

// tanh(x) = 1 - 2/(exp(2x)+1); exp(2x) = exp2(x * 2*log2(e)).
__device__ __forceinline__ float fast_tanh(float x) {
  float e = __builtin_amdgcn_exp2f(x * 2.8853900817779268f);
  return 1.0f - 2.0f * __builtin_amdgcn_rcpf(e + 1.0f);
}

// v_dot2_f32_f16: 2 fp16 MACs with f32 accumulate in one VALU op.
__device__ __forceinline__ float dot2(h2 a, h2 b, float c) {
#if __has_builtin(__builtin_amdgcn_fdot2)
  return __builtin_amdgcn_fdot2(a, b, c, false);
#else
  return c + (float)a[0] * (float)b[0] + (float)a[1] * (float)b[1];
#endif
}

__device__ __forceinline__ h2 pack2(float lo, float hi) {
#if __has_builtin(__builtin_amdgcn_cvt_pkrtz)
  return __builtin_amdgcn_cvt_pkrtz(lo, hi);
#else
  h2 r; r[0] = (half_t)lo; r[1] = (half_t)hi; return r;
#endif
}

#define PIN(v) asm volatile("" : "+v"(v))

// Pack one f32 weight row (stride STR, N2 half2 pairs) into resident half2 VGPRs.
#define LOADW(DST, SRC, STR, N2)                                    \
  _Pragma("unroll") for (int k = 0; k < (N2); ++k) {                \
    DST[k][0] = (half_t)SRC[jr * (STR) + 2 * k];                    \
    DST[k][1] = (half_t)SRC[jr * (STR) + 2 * k + 1];                \
    PIN(DST[k]);                                                    \
  }

// 40-wide dot of preloaded h8 block Q[OFF..OFF+4] against weight h2 array W[20].
// h2 extracts are register-pair aligned -> free.
#define HD4O(Q, OFF, W, A0, A1, A2, A3)                             \
  _Pragma("unroll") for (int m = 0; m < 5; ++m) {                   \
    h2 p0 = {Q[(OFF) + m][0], Q[(OFF) + m][1]};                     \
    h2 p1 = {Q[(OFF) + m][2], Q[(OFF) + m][3]};                     \
    h2 p2 = {Q[(OFF) + m][4], Q[(OFF) + m][5]};                     \
    h2 p3 = {Q[(OFF) + m][6], Q[(OFF) + m][7]};                     \
    A0 = dot2(p0, (W)[4 * m + 0], A0);                              \
    A1 = dot2(p1, (W)[4 * m + 1], A1);                              \
    A2 = dot2(p2, (W)[4 * m + 2], A2);                              \
    A3 = dot2(p3, (W)[4 * m + 3], A3);                              \
  }

// Issue next-tick LDS broadcast reads into Q[15] (q0=h0, q1=h1, q2=h2).
#define PRELOADQ(Q, SLAB, N0, N1, N2) do {                          \
  if (N0) { _Pragma("unroll") for (int m = 0; m < 5; ++m)           \
      Q[m]      = ((const h8*)&SLAB[0][0])[m]; }                    \
  if (N1) { _Pragma("unroll") for (int m = 0; m < 5; ++m)           \
      Q[5 + m]  = ((const h8*)&SLAB[1][0])[m]; }                    \
  if (N2) { _Pragma("unroll") for (int m = 0; m < 5; ++m)           \
      Q[10 + m] = ((const h8*)&SLAB[2][0])[m]; }                    \
} while (0)

// Skewed tick for one batch stream: h0[u] (D0), h1[u-1] (D1), h2[u-2] (D2).
// Consumes preloaded Q; writes new h to SLAB at the end (same-wave DS in-order
// -> the following PRELOADQ sees the new values).
#define TICKC(D0, D1, D2, Q, XH, SLAB, NH2) do {                    \
  float a0=0.f,a1=0.f,a2=0.f,a3=0.f;                                \
  float b0=0.f,b1=0.f,b2=0.f,b3=0.f;                                \
  float c0=0.f,c1=0.f,c2=0.f,c3=0.f;                                \
  float nh0=0.f, nh1=0.f;                                           \
  if (D0) {                                                         \
    a0 = bias0;                                                     \
    a0=dot2(XH[0],w0i[0],a0); a1=dot2(XH[1],w0i[1],a1);             \
    a2=dot2(XH[2],w0i[2],a2); a3=dot2(XH[3],w0i[3],a3);             \
    a0=dot2(XH[4],w0i[4],a0); a1=dot2(XH[5],w0i[5],a1);             \
    a2=dot2(XH[6],w0i[6],a2); a3=dot2(XH[7],w0i[7],a3);             \
    HD4O(Q, 0, w0h, a0,a1,a2,a3)    /* h0[u-1] */                   \
  }                                                                 \
  if (D1) {                                                         \
    b0 = bias1;                                                     \
    HD4O(Q, 0, w1i, b0,b1,b2,b3)    /* h0[u-1] */                   \
    HD4O(Q, 5, w1h, b0,b1,b2,b3)    /* h1[u-2] */                   \
  }                                                                 \
  if (D2) {                                                         \
    c0 = bias2;                                                     \
    HD4O(Q, 5,  w2i, c0,c1,c2,c3)   /* h1[u-2] */                   \
    HD4O(Q, 10, w2h, c0,c1,c2,c3)   /* h2[u-3] */                   \
  }                                                                 \
  if (D0) nh0 = fast_tanh((a0 + a1) + (a2 + a3));                   \
  if (D1) nh1 = fast_tanh((b0 + b1) + (b2 + b3));                   \
  if (D2) NH2 = fast_tanh((c0 + c1) + (c2 + c3));                   \
  if (D0) SLAB[0][j] = (half_t)nh0;                                 \
  if (D1) SLAB[1][j] = (half_t)nh1;                                 \
  if (D2) SLAB[2][j] = (half_t)NH2;                                 \
} while (0)

__device__ __forceinline__ void loadx(h2* xh, const float* __restrict__ p) {
  float4 f0 = ((const float4*)p)[0];
  float4 f1 = ((const float4*)p)[1];
  float4 f2 = ((const float4*)p)[2];
  float4 f3 = ((const float4*)p)[3];
  xh[0] = pack2(f0.x, f0.y); xh[1] = pack2(f0.z, f0.w);
  xh[2] = pack2(f1.x, f1.y); xh[3] = pack2(f1.z, f1.w);
  xh[4] = pack2(f2.x, f2.y); xh[5] = pack2(f2.z, f2.w);
  xh[6] = pack2(f3.x, f3.y); xh[7] = pack2(f3.z, f3.w);
}

__global__ __launch_bounds__(64)
__attribute__((amdgpu_waves_per_eu(1, 1)))  // full 512-reg budget
void rnn3_fused(const float* __restrict__ x,
                const float* __restrict__ wih0, const float* __restrict__ whh0,
                const float* __restrict__ bih0, const float* __restrict__ bhh0,
                const float* __restrict__ wih1, const float* __restrict__ whh1,
                const float* __restrict__ b_ih1, const float* __restrict__ bhh1,
                const float* __restrict__ wih2, const float* __restrict__ whh2,
                const float* __restrict__ bih2, const float* __restrict__ bhh2,
                const float* __restrict__ fcw, const float* __restrict__ fcb,
                float* __restrict__ out) {
  const int b0 = 2 * blockIdx.x;           // this wave runs batches b0, b0+1
  const int j = threadIdx.x;               // lane = hidden unit (j < 40 real)
  const int jr = (j < H_) ? j : (H_ - 1);  // lanes 40..63 duplicate unit 39

  // ---- weights packed fp16: 108 resident VGPRs/lane, shared by both streams ----
  h2 w0i[I_ / 2], w0h[H_ / 2], w1i[H_ / 2], w1h[H_ / 2], w2i[H_ / 2], w2h[H_ / 2];
  LOADW(w0i, wih0, I_, I_ / 2)
  LOADW(w0h, whh0, H_, H_ / 2)
  LOADW(w1i, wih1, H_, H_ / 2)
  LOADW(w1h, whh1, H_, H_ / 2)
  LOADW(w2i, wih2, H_, H_ / 2)
  LOADW(w2h, whh2, H_, H_ / 2)

  float bias0 = bih0[jr] + bhh0[jr];  PIN(bias0);
  float bias1 = b_ih1[jr] + bhh1[jr]; PIN(bias1);
  float bias2 = bih2[jr] + bhh2[jr];  PIN(bias2);

  // per-stream h slabs (fp16 broadcast buffers)
  __shared__ __align__(16) half_t hsA[3][64];
  __shared__ __align__(16) half_t hsB[3][64];
  hsA[0][j] = (half_t)0.f; hsA[1][j] = (half_t)0.f; hsA[2][j] = (half_t)0.f;
  hsB[0][j] = (half_t)0.f; hsB[1][j] = (half_t)0.f; hsB[2][j] = (half_t)0.f;
  __syncthreads();

  const float* __restrict__ xp0 = x + (size_t)b0 * (T_ * I_);
  const float* __restrict__ xp1 = xp0 + (size_t)(T_ * I_);

  // per-stream x prefetch (distance 2)
  h2 xA0[8], xB0[8], xA1[8], xB1[8];
  loadx(xA0, xp0); loadx(xB0, xp0 + I_);
  loadx(xA1, xp1); loadx(xB1, xp1 + I_);

  float nh2a = 0.f, nh2b = 0.f;
  h8 qa[15], qb[15];

  PRELOADQ(qa, hsA, 1, 0, 0);   // tick 0 needs only q0 (zeros)
  PRELOADQ(qb, hsB, 1, 0, 0);

  // tick 0: (1,0,0) -> preload for tick 1 (1,1,0)
  TICKC(1,0,0, qa, xA0, hsA, nh2a); PRELOADQ(qa, hsA, 1,1,0); loadx(xA0, xp0 + 2*I_);
  TICKC(1,0,0, qb, xA1, hsB, nh2b); PRELOADQ(qb, hsB, 1,1,0); loadx(xA1, xp1 + 2*I_);
  // tick 1: (1,1,0) -> preload for tick 2 (1,1,1)
  TICKC(1,1,0, qa, xB0, hsA, nh2a); PRELOADQ(qa, hsA, 1,1,1); loadx(xB0, xp0 + 3*I_);
  TICKC(1,1,0, qb, xB1, hsB, nh2b); PRELOADQ(qb, hsB, 1,1,1); loadx(xB1, xp1 + 3*I_);

  // steady state: ticks 2 .. T-1 (2046 ticks, 2 per iteration).
  // b1's compute covers b0's LDS write->read turnaround and vice versa.
  for (int u = 2; u < T_; u += 2) {
    const int tf0 = (u + 2 < T_) ? u + 2 : T_ - 1;
    TICKC(1,1,1, qa, xA0, hsA, nh2a); PRELOADQ(qa, hsA, 1,1,1);
    loadx(xA0, xp0 + (size_t)tf0 * I_);
    TICKC(1,1,1, qb, xA1, hsB, nh2b); PRELOADQ(qb, hsB, 1,1,1);
    loadx(xA1, xp1 + (size_t)tf0 * I_);
    const int tf1 = (u + 3 < T_) ? u + 3 : T_ - 1;
    TICKC(1,1,1, qa, xB0, hsA, nh2a); PRELOADQ(qa, hsA, 1,1,1);
    loadx(xB0, xp0 + (size_t)tf1 * I_);
    TICKC(1,1,1, qb, xB1, hsB, nh2b); PRELOADQ(qb, hsB, 1,1,1);
    loadx(xB1, xp1 + (size_t)tf1 * I_);
  }

  // tick T: (0,1,1) -> preload for tick T+1 (0,0,1): q1,q2
  TICKC(0,1,1, qa, xA0, hsA, nh2a); PRELOADQ(qa, hsA, 0,1,1);
  TICKC(0,1,1, qb, xA1, hsB, nh2b); PRELOADQ(qb, hsB, 0,1,1);
  // tick T+1: (0,0,1) -> final h2[T-1]
  TICKC(0,0,1, qa, xA0, hsA, nh2a);
  TICKC(0,0,1, qb, xA1, hsB, nh2b);

  // ---- FC head for both streams ----
  const float fw = (j < H_) ? fcw[j] : 0.f;  // dup lanes contribute 0
  float va = nh2a * fw;
  float vb = nh2b * fw;
#pragma unroll
  for (int off = 32; off > 0; off >>= 1) {
    va += __shfl_down(va, off);
    vb += __shfl_down(vb, off);
  }
  if (j == 0) {
    const float fb = fcb[0];
    out[b0]     = va + fb;
    out[b0 + 1] = vb + fb;
  }
}

extern "C" void kernel_launch(void* const* d_in, const int* in_sizes, int n_in,
                              void* d_out, int out_size, void* d_ws, size_t ws_size,
                              hipStream_t stream) {
  (void)in_sizes; (void)n_in; (void)d_ws; (void)ws_size; (void)out_size;
  const float* x    = (const float*)d_in[0];
  const float* wih0 = (const float*)d_in[1];
  const float* whh0 = (const float*)d_in[2];
  const float* bih0 = (const float*)d_in[3];
  const float* bhh0 = (const float*)d_in[4];
  const float* wih1 = (const float*)d_in[5];
  const float* whh1 = (const float*)d_in[6];
  const float* bih1 = (const float*)d_in[7];
  const float* bhh1 = (const float*)d_in[8];
  const float* wih2 = (const float*)d_in[9];
  const float* whh2 = (const float*)d_in[10];
  const float* bih2 = (const float*)d_in[11];
  const float* bhh2 = (const float*)d_in[12];
  const float* fcw  = (const float*)d_in[13];
  const float* fcb  = (const float*)d_in[14];
  float* out = (float*)d_out;

  hipLaunchKernelGGL(rnn3_fused, dim3(B_ / 2), dim3(64), 0, stream,
                     x, wih0, whh0, bih0, bhh0,
                     wih1, whh1, bih1, bhh1,
                     wih2, whh2, bih2, bhh2,
                     fcw, fcb, out);
}

// Round 7
// 1345.808 us; speedup vs baseline: 1.7445x; 1.7445x over previous
//
#include <hip/hip_runtime.h>
#include <cstddef>
#include <cstdint>

#define B_ 512
#define T_ 2048
#define I_ 16
#define H_ 40

typedef __fp16 half_t;  // matches __builtin_amdgcn_* vector element type exactly
typedef half_t h2 __attribute__((ext_vector_type(2)));
typedef half_t h8 __attribute__((ext_vector_type(8)));

// tanh(x) = 1 - 2/(exp(2x)+1); exp(2x) = exp2(x * 2*log2(e)).
__device__ __forceinline__ float fast_tanh(float x) {
  float e = __builtin_amdgcn_exp2f(x * 2.8853900817779268f);
  return 1.0f - 2.0f * __builtin_amdgcn_rcpf(e + 1.0f);
}

// v_dot2_f32_f16: 2 fp16 MACs with f32 accumulate in one VALU op.
__device__ __forceinline__ float dot2(h2 a, h2 b, float c) {
#if __has_builtin(__builtin_amdgcn_fdot2)
  return __builtin_amdgcn_fdot2(a, b, c, false);
#else
  return c + (float)a[0] * (float)b[0] + (float)a[1] * (float)b[1];
#endif
}

// Use-site fp16 pack via volatile asm: CANNOT be hoisted back next to the
// global load, so the vmcnt wait lands here (data long arrived) instead of
// immediately after the load issue (r4-r6 failure: full HBM latency bubble
// inside every tick).
__device__ __forceinline__ h2 cvtpk(float lo, float hi) {
  h2 r;
  asm volatile("v_cvt_pkrtz_f16_f32 %0, %1, %2" : "=v"(r) : "v"(lo), "v"(hi));
  return r;
}

#define PIN(v) asm volatile("" : "+v"(v))

// Pack one f32 weight row (stride STR, N2 half2 pairs) into resident half2 VGPRs.
#define LOADW(DST, SRC, STR, N2)                                    \
  _Pragma("unroll") for (int k = 0; k < (N2); ++k) {                \
    DST[k][0] = (half_t)SRC[jr * (STR) + 2 * k];                    \
    DST[k][1] = (half_t)SRC[jr * (STR) + 2 * k + 1];                \
    PIN(DST[k]);                                                    \
  }

// 40-wide dot against LDS-broadcast h (fp16): 5 uniform 16B reads, 20 dot2.
// h2 extracts are register-pair aligned -> zero shuffle cost.
#define HD(HP, W)                                                   \
  do {                                                              \
    _Pragma("unroll") for (int m = 0; m < 5; ++m) {                 \
      h8 q = (HP)[m];                                               \
      h2 p0 = {q[0], q[1]}, p1 = {q[2], q[3]};                      \
      h2 p2 = {q[4], q[5]}, p3 = {q[6], q[7]};                      \
      a0 = dot2(p0, (W)[4 * m + 0], a0);                            \
      a1 = dot2(p1, (W)[4 * m + 1], a1);                            \
      a2 = dot2(p2, (W)[4 * m + 2], a2);                            \
      a3 = dot2(p3, (W)[4 * m + 3], a3);                            \
    }                                                               \
  } while (0)

// One RNN time step (3 layers), serial (round-4 structure, best measured).
// Same-wave DS ops are in-order: the b16 write of new h is visible to the
// immediately following uniform reads.
#define STEP(XH)                                                    \
  do {                                                              \
    const h8* hp0 = (const h8*)&hb16[0][0];                         \
    const h8* hp1 = (const h8*)&hb16[1][0];                         \
    const h8* hp2 = (const h8*)&hb16[2][0];                         \
    /* ---- layer 0 ---- */                                         \
    float a0 = bias0, a1 = 0.f, a2 = 0.f, a3 = 0.f;                 \
    a0 = dot2(XH[0], w0i[0], a0); a1 = dot2(XH[1], w0i[1], a1);     \
    a2 = dot2(XH[2], w0i[2], a2); a3 = dot2(XH[3], w0i[3], a3);     \
    a0 = dot2(XH[4], w0i[4], a0); a1 = dot2(XH[5], w0i[5], a1);     \
    a2 = dot2(XH[6], w0i[6], a2); a3 = dot2(XH[7], w0i[7], a3);     \
    HD(hp0, w0h); /* old h0 */                                      \
    const float nh0 = fast_tanh((a0 + a1) + (a2 + a3));             \
    hb16[0][j] = (half_t)nh0;                                       \
    /* ---- layer 1 ---- */                                         \
    a0 = bias1; a1 = a2 = a3 = 0.f;                                 \
    HD(hp0, w1i); /* NEW h0 */                                      \
    HD(hp1, w1h); /* old h1 */                                      \
    const float nh1 = fast_tanh((a0 + a1) + (a2 + a3));             \
    hb16[1][j] = (half_t)nh1;                                       \
    /* ---- layer 2 ---- */                                         \
    a0 = bias2; a1 = a2 = a3 = 0.f;                                 \
    HD(hp1, w2i); /* NEW h1 */                                      \
    HD(hp2, w2h); /* old h2 */                                      \
    nh2v = fast_tanh((a0 + a1) + (a2 + a3));                        \
    hb16[2][j] = (half_t)nh2v;                                      \
  } while (0)

// Raw x prefetch: 4 global_load_dwordx4 into named float4 regs, NO dependent
// ops -> no wait here. P is wave-uniform.
#define LOADRAW(R0, R1, R2, R3, P)                                  \
  do {                                                              \
    const float4* q_ = (const float4*)(P);                          \
    R0 = q_[0]; R1 = q_[1]; R2 = q_[2]; R3 = q_[3];                 \
  } while (0)

// Use-site pack of one raw x buffer into h2[8] (8 volatile cvt instrs).
#define PACKX(XH, R0, R1, R2, R3)                                   \
  do {                                                              \
    XH[0] = cvtpk(R0.x, R0.y); XH[1] = cvtpk(R0.z, R0.w);           \
    XH[2] = cvtpk(R1.x, R1.y); XH[3] = cvtpk(R1.z, R1.w);           \
    XH[4] = cvtpk(R2.x, R2.y); XH[5] = cvtpk(R2.z, R2.w);           \
    XH[6] = cvtpk(R3.x, R3.y); XH[7] = cvtpk(R3.z, R3.w);           \
  } while (0)

__global__ __launch_bounds__(64)
__attribute__((amdgpu_waves_per_eu(1, 1)))  // full 512-reg budget (r4: confirmed, 132 VGPR)
void rnn3_fused(const float* __restrict__ x,
                const float* __restrict__ wih0, const float* __restrict__ whh0,
                const float* __restrict__ bih0, const float* __restrict__ bhh0,
                const float* __restrict__ wih1, const float* __restrict__ whh1,
                const float* __restrict__ b_ih1, const float* __restrict__ bhh1,
                const float* __restrict__ wih2, const float* __restrict__ whh2,
                const float* __restrict__ bih2, const float* __restrict__ bhh2,
                const float* __restrict__ fcw, const float* __restrict__ fcb,
                float* __restrict__ out) {
  const int b = blockIdx.x;
  const int j = threadIdx.x;               // lane = hidden unit (j < 40 real)
  const int jr = (j < H_) ? j : (H_ - 1);  // lanes 40..63 duplicate unit 39

  // ---- weights packed fp16: 108 resident VGPRs/lane ----
  h2 w0i[I_ / 2], w0h[H_ / 2], w1i[H_ / 2], w1h[H_ / 2], w2i[H_ / 2], w2h[H_ / 2];
  LOADW(w0i, wih0, I_, I_ / 2)
  LOADW(w0h, whh0, H_, H_ / 2)
  LOADW(w1i, wih1, H_, H_ / 2)
  LOADW(w1h, whh1, H_, H_ / 2)
  LOADW(w2i, wih2, H_, H_ / 2)
  LOADW(w2h, whh2, H_, H_ / 2)

  float bias0 = bih0[jr] + bhh0[jr];  PIN(bias0);
  float bias1 = b_ih1[jr] + bhh1[jr]; PIN(bias1);
  float bias2 = bih2[jr] + bhh2[jr];  PIN(bias2);

  // h broadcast in fp16: uniform 16B reads = 5 reads per 40-vector, conflict-free.
  __shared__ __align__(16) half_t hb16[3][64];
  hb16[0][j] = (half_t)0.f; hb16[1][j] = (half_t)0.f; hb16[2][j] = (half_t)0.f;
  __syncthreads();

  const float* __restrict__ xb = x + (size_t)b * (T_ * I_);

  // 4 raw float4 buffers (64 VGPR), distance-4 prefetch, unroll-4.
  float4 rA0, rA1, rA2, rA3, rB0, rB1, rB2, rB3;
  float4 rC0, rC1, rC2, rC3, rD0, rD1, rD2, rD3;
  LOADRAW(rA0, rA1, rA2, rA3, xb + 0 * I_);
  LOADRAW(rB0, rB1, rB2, rB3, xb + 1 * I_);
  LOADRAW(rC0, rC1, rC2, rC3, xb + 2 * I_);
  LOADRAW(rD0, rD1, rD2, rD3, xb + 3 * I_);

  float nh2v = 0.f;
  h2 xh[8];

  for (int t = 0; t < T_; t += 4) {   // T_ % 4 == 0
    PACKX(xh, rA0, rA1, rA2, rA3);
    STEP(xh);
    { const int tf = (t + 4 < T_) ? t + 4 : T_ - 1; LOADRAW(rA0, rA1, rA2, rA3, xb + (size_t)tf * I_); }
    PACKX(xh, rB0, rB1, rB2, rB3);
    STEP(xh);
    { const int tf = (t + 5 < T_) ? t + 5 : T_ - 1; LOADRAW(rB0, rB1, rB2, rB3, xb + (size_t)tf * I_); }
    PACKX(xh, rC0, rC1, rC2, rC3);
    STEP(xh);
    { const int tf = (t + 6 < T_) ? t + 6 : T_ - 1; LOADRAW(rC0, rC1, rC2, rC3, xb + (size_t)tf * I_); }
    PACKX(xh, rD0, rD1, rD2, rD3);
    STEP(xh);
    { const int tf = (t + 7 < T_) ? t + 7 : T_ - 1; LOADRAW(rD0, rD1, rD2, rD3, xb + (size_t)tf * I_); }
  }

  // ---- FC head: out[b] = sum_j fc_w[j]*h2[j] + fc_b ----
  const float fw = (j < H_) ? fcw[j] : 0.f;  // dup lanes (40..63) contribute 0
  float v = nh2v * fw;
#pragma unroll
  for (int off = 32; off > 0; off >>= 1) v += __shfl_down(v, off);
  if (j == 0) out[b] = v + fcb[0];
}

extern "C" void kernel_launch(void* const* d_in, const int* in_sizes, int n_in,
                              void* d_out, int out_size, void* d_ws, size_t ws_size,
                              hipStream_t stream) {
  (void)in_sizes; (void)n_in; (void)d_ws; (void)ws_size; (void)out_size;
  const float* x    = (const float*)d_in[0];
  const float* wih0 = (const float*)d_in[1];
  const float* whh0 = (const float*)d_in[2];
  const float* bih0 = (const float*)d_in[3];
  const float* bhh0 = (const float*)d_in[4];
  const float* wih1 = (const float*)d_in[5];
  const float* whh1 = (const float*)d_in[6];
  const float* bih1 = (const float*)d_in[7];
  const float* bhh1 = (const float*)d_in[8];
  const float* wih2 = (const float*)d_in[9];
  const float* whh2 = (const float*)d_in[10];
  const float* bih2 = (const float*)d_in[11];
  const float* bhh2 = (const float*)d_in[12];
  const float* fcw  = (const float*)d_in[13];
  const float* fcb  = (const float*)d_in[14];
  float* out = (float*)d_out;

  hipLaunchKernelGGL(rnn3_fused, dim3(B_), dim3(64), 0, stream,
                     x, wih0, whh0, bih0, bhh0,
                     wih1, whh1, bih1, bhh1,
                     wih2, whh2, bih2, bhh2,
                     fcw, fcb, out);
}

// Round 9
// 1106.215 us; speedup vs baseline: 2.1224x; 1.2166x over previous
//
#include <hip/hip_runtime.h>
#include <cstddef>
#include <cstdint>

#define B_ 512
#define T_ 2048
#define I_ 16
#define H_ 40

typedef __fp16 half_t;  // matches __builtin_amdgcn_* vector element type exactly
typedef half_t h2 __attribute__((ext_vector_type(2)));
typedef half_t h8 __attribute__((ext_vector_type(8)));
typedef float f4 __attribute__((ext_vector_type(4)));  // asm-constraint-compatible 128b reg quad

// tanh(x) = 1 - 2/(exp(2x)+1); exp(2x) = exp2(x * 2*log2(e)).
__device__ __forceinline__ float fast_tanh(float x) {
  float e = __builtin_amdgcn_exp2f(x * 2.8853900817779268f);
  return 1.0f - 2.0f * __builtin_amdgcn_rcpf(e + 1.0f);
}

// v_dot2_f32_f16: 2 fp16 MACs with f32 accumulate in one VALU op.
__device__ __forceinline__ float dot2(h2 a, h2 b, float c) {
#if __has_builtin(__builtin_amdgcn_fdot2)
  return __builtin_amdgcn_fdot2(a, b, c, false);
#else
  return c + (float)a[0] * (float)b[0] + (float)a[1] * (float)b[1];
#endif
}

// Use-site fp16 pack (volatile: fixed position, ordered vs other volatile asm).
__device__ __forceinline__ h2 cvtpk(float lo, float hi) {
  h2 r;
  asm volatile("v_cvt_pkrtz_f16_f32 %0, %1, %2" : "=v"(r) : "v"(lo), "v"(hi));
  return r;
}

#define PIN(v) asm volatile("" : "+v"(v))

// ASYNC x prefetch: 4 global_load_dwordx4 issued via volatile asm -> the
// compiler CANNOT sink these to use-site (r7 failure: non-volatile loads were
// sunk next to the pack, exposing full HBM latency every step). Outputs are
// written asynchronously when the loads return; consumption must follow a
// counted s_waitcnt vmcnt (WAITX); registers stay live until final drain.
#define GLOAD16(R0, R1, R2, R3, P)                                  \
  asm volatile("global_load_dwordx4 %0, %4, off\n\t"                \
               "global_load_dwordx4 %1, %4, off offset:16\n\t"      \
               "global_load_dwordx4 %2, %4, off offset:32\n\t"      \
               "global_load_dwordx4 %3, %4, off offset:48"          \
               : "=&v"(R0), "=&v"(R1), "=&v"(R2), "=&v"(R3)         \
               : "v"(P))

// Counted drain: wait until <=N VMEM ops outstanding. sched_barrier stops the
// compiler hoisting dependent ops above the wait (guide rule #18).
#define WAITX(N)                                                    \
  do {                                                              \
    asm volatile("s_waitcnt vmcnt(" #N ")" ::: "memory");           \
    __builtin_amdgcn_sched_barrier(0);                              \
  } while (0)

// Pack one f32 weight row (stride STR, N2 half2 pairs) into resident half2 VGPRs.
#define LOADW(DST, SRC, STR, N2)                                    \
  _Pragma("unroll") for (int k = 0; k < (N2); ++k) {                \
    DST[k][0] = (half_t)SRC[jr * (STR) + 2 * k];                    \
    DST[k][1] = (half_t)SRC[jr * (STR) + 2 * k + 1];                \
    PIN(DST[k]);                                                    \
  }

// 40-wide dot against LDS-broadcast h (fp16): 5 uniform 16B reads, 20 dot2.
#define HD(HP, W)                                                   \
  do {                                                              \
    _Pragma("unroll") for (int m = 0; m < 5; ++m) {                 \
      h8 q = (HP)[m];                                               \
      h2 p0 = {q[0], q[1]}, p1 = {q[2], q[3]};                      \
      h2 p2 = {q[4], q[5]}, p3 = {q[6], q[7]};                      \
      a0 = dot2(p0, (W)[4 * m + 0], a0);                            \
      a1 = dot2(p1, (W)[4 * m + 1], a1);                            \
      a2 = dot2(p2, (W)[4 * m + 2], a2);                            \
      a3 = dot2(p3, (W)[4 * m + 3], a3);                            \
    }                                                               \
  } while (0)

// One RNN time step (3 layers), serial (round-4 structure, best measured).
// Same-wave DS ops are in-order: the b16 write of new h is visible to the
// immediately following uniform reads.
#define STEP(XH)                                                    \
  do {                                                              \
    const h8* hp0 = (const h8*)&hb16[0][0];                         \
    const h8* hp1 = (const h8*)&hb16[1][0];                         \
    const h8* hp2 = (const h8*)&hb16[2][0];                         \
    /* ---- layer 0 ---- */                                         \
    float a0 = bias0, a1 = 0.f, a2 = 0.f, a3 = 0.f;                 \
    a0 = dot2(XH[0], w0i[0], a0); a1 = dot2(XH[1], w0i[1], a1);     \
    a2 = dot2(XH[2], w0i[2], a2); a3 = dot2(XH[3], w0i[3], a3);     \
    a0 = dot2(XH[4], w0i[4], a0); a1 = dot2(XH[5], w0i[5], a1);     \
    a2 = dot2(XH[6], w0i[6], a2); a3 = dot2(XH[7], w0i[7], a3);     \
    HD(hp0, w0h); /* old h0 */                                      \
    const float nh0 = fast_tanh((a0 + a1) + (a2 + a3));             \
    hb16[0][j] = (half_t)nh0;                                       \
    /* ---- layer 1 ---- */                                         \
    a0 = bias1; a1 = a2 = a3 = 0.f;                                 \
    HD(hp0, w1i); /* NEW h0 */                                      \
    HD(hp1, w1h); /* old h1 */                                      \
    const float nh1 = fast_tanh((a0 + a1) + (a2 + a3));             \
    hb16[1][j] = (half_t)nh1;                                       \
    /* ---- layer 2 ---- */                                         \
    a0 = bias2; a1 = a2 = a3 = 0.f;                                 \
    HD(hp1, w2i); /* NEW h1 */                                      \
    HD(hp2, w2h); /* old h2 */                                      \
    nh2v = fast_tanh((a0 + a1) + (a2 + a3));                        \
    hb16[2][j] = (half_t)nh2v;                                      \
  } while (0)

// Use-site pack of one raw x buffer into h2[8].
#define PACKX(XH, R0, R1, R2, R3)                                   \
  do {                                                              \
    XH[0] = cvtpk(R0[0], R0[1]); XH[1] = cvtpk(R0[2], R0[3]);       \
    XH[2] = cvtpk(R1[0], R1[1]); XH[3] = cvtpk(R1[2], R1[3]);       \
    XH[4] = cvtpk(R2[0], R2[1]); XH[5] = cvtpk(R2[2], R2[3]);       \
    XH[6] = cvtpk(R3[0], R3[1]); XH[7] = cvtpk(R3[2], R3[3]);       \
  } while (0)

__global__ __launch_bounds__(64)
__attribute__((amdgpu_waves_per_eu(1, 1)))  // full 512-reg budget
void rnn3_fused(const float* __restrict__ x,
                const float* __restrict__ wih0, const float* __restrict__ whh0,
                const float* __restrict__ bih0, const float* __restrict__ bhh0,
                const float* __restrict__ wih1, const float* __restrict__ whh1,
                const float* __restrict__ b_ih1, const float* __restrict__ bhh1,
                const float* __restrict__ wih2, const float* __restrict__ whh2,
                const float* __restrict__ bih2, const float* __restrict__ bhh2,
                const float* __restrict__ fcw, const float* __restrict__ fcb,
                float* __restrict__ out) {
  const int b = blockIdx.x;
  const int j = threadIdx.x;               // lane = hidden unit (j < 40 real)
  const int jr = (j < H_) ? j : (H_ - 1);  // lanes 40..63 duplicate unit 39

  // ---- weights packed fp16: 108 resident VGPRs/lane ----
  h2 w0i[I_ / 2], w0h[H_ / 2], w1i[H_ / 2], w1h[H_ / 2], w2i[H_ / 2], w2h[H_ / 2];
  LOADW(w0i, wih0, I_, I_ / 2)
  LOADW(w0h, whh0, H_, H_ / 2)
  LOADW(w1i, wih1, H_, H_ / 2)
  LOADW(w1h, whh1, H_, H_ / 2)
  LOADW(w2i, wih2, H_, H_ / 2)
  LOADW(w2h, whh2, H_, H_ / 2)

  float bias0 = bih0[jr] + bhh0[jr];  PIN(bias0);
  float bias1 = b_ih1[jr] + bhh1[jr]; PIN(bias1);
  float bias2 = bih2[jr] + bhh2[jr];  PIN(bias2);

  // h broadcast in fp16: uniform 16B reads = 5 reads per 40-vector, conflict-free.
  __shared__ __align__(16) half_t hb16[3][64];
  hb16[0][j] = (half_t)0.f; hb16[1][j] = (half_t)0.f; hb16[2][j] = (half_t)0.f;
  __syncthreads();

  const float* __restrict__ xb = x + (size_t)b * (T_ * I_);

  // Two async 64B buffers, distance-2. Invariant: 8 loads outstanding;
  // WAITX(4) drains exactly the buffer about to be consumed (issued a full
  // step ago -> latency hidden).
  f4 rA0, rA1, rA2, rA3, rB0, rB1, rB2, rB3;
  GLOAD16(rA0, rA1, rA2, rA3, xb + 0 * I_);   // t = 0
  GLOAD16(rB0, rB1, rB2, rB3, xb + 1 * I_);   // t = 1

  float nh2v = 0.f;
  h2 xh[8];

  for (int t = 0; t < T_; t += 2) {
    WAITX(4);                     // A ready (B still in flight)
    PACKX(xh, rA0, rA1, rA2, rA3);
    STEP(xh);
    { const float* pf = xb + (size_t)((t + 2 < T_) ? t + 2 : T_ - 1) * I_;
      GLOAD16(rA0, rA1, rA2, rA3, pf); }
    WAITX(4);                     // B ready (new A in flight)
    PACKX(xh, rB0, rB1, rB2, rB3);
    STEP(xh);
    { const float* pf = xb + (size_t)((t + 3 < T_) ? t + 3 : T_ - 1) * I_;
      GLOAD16(rB0, rB1, rB2, rB3, pf); }
  }

  // Drain all async loads BEFORE their destination registers can be
  // reallocated (in-flight returns would corrupt reused regs).
  asm volatile("s_waitcnt vmcnt(0)" ::: "memory");
  __builtin_amdgcn_sched_barrier(0);
  PIN(rA0); PIN(rA1); PIN(rA2); PIN(rA3);
  PIN(rB0); PIN(rB1); PIN(rB2); PIN(rB3);

  // ---- FC head: out[b] = sum_j fc_w[j]*h2[j] + fc_b ----
  const float fw = (j < H_) ? fcw[j] : 0.f;  // dup lanes (40..63) contribute 0
  float v = nh2v * fw;
#pragma unroll
  for (int off = 32; off > 0; off >>= 1) v += __shfl_down(v, off);
  if (j == 0) out[b] = v + fcb[0];
}

extern "C" void kernel_launch(void* const* d_in, const int* in_sizes, int n_in,
                              void* d_out, int out_size, void* d_ws, size_t ws_size,
                              hipStream_t stream) {
  (void)in_sizes; (void)n_in; (void)d_ws; (void)ws_size; (void)out_size;
  const float* x    = (const float*)d_in[0];
  const float* wih0 = (const float*)d_in[1];
  const float* whh0 = (const float*)d_in[2];
  const float* bih0 = (const float*)d_in[3];
  const float* bhh0 = (const float*)d_in[4];
  const float* wih1 = (const float*)d_in[5];
  const float* whh1 = (const float*)d_in[6];
  const float* bih1 = (const float*)d_in[7];
  const float* bhh1 = (const float*)d_in[8];
  const float* wih2 = (const float*)d_in[9];
  const float* whh2 = (const float*)d_in[10];
  const float* bih2 = (const float*)d_in[11];
  const float* bhh2 = (const float*)d_in[12];
  const float* fcw  = (const float*)d_in[13];
  const float* fcb  = (const float*)d_in[14];
  float* out = (float*)d_out;

  hipLaunchKernelGGL(rnn3_fused, dim3(B_), dim3(64), 0, stream,
                     x, wih0, whh0, bih0, bhh0,
                     wih1, whh1, bih1, bhh1,
                     wih2, whh2, bih2, bhh2,
                     fcw, fcb, out);
}

// Round 10
// 926.287 us; speedup vs baseline: 2.5346x; 1.1942x over previous
//
#include <hip/hip_runtime.h>
#include <cstddef>
#include <cstdint>

#define B_ 512
#define T_ 2048
#define I_ 16
#define H_ 40

typedef __fp16 half_t;  // matches __builtin_amdgcn_* vector element type exactly
typedef half_t h2 __attribute__((ext_vector_type(2)));
typedef float f4 __attribute__((ext_vector_type(4)));  // asm-constraint-compatible 128b reg quad

// tanh(x) = 1 - 2/(exp(2x)+1); exp(2x) = exp2(x * 2*log2(e)).
__device__ __forceinline__ float fast_tanh(float x) {
  float e = __builtin_amdgcn_exp2f(x * 2.8853900817779268f);
  return 1.0f - 2.0f * __builtin_amdgcn_rcpf(e + 1.0f);
}

// v_dot2_f32_f16: 2 fp16 MACs with f32 accumulate. One src may be SGPR-uniform.
__device__ __forceinline__ float dot2(h2 a, h2 b, float c) {
  return __builtin_amdgcn_fdot2(a, b, c, false);
}

// Use-site fp16 pack for x (volatile: pins the vmcnt wait at use-site, r9-proven).
__device__ __forceinline__ h2 cvtpk_v(float lo, float hi) {
  h2 r;
  asm volatile("v_cvt_pkrtz_f16_f32 %0, %1, %2" : "=v"(r) : "v"(lo), "v"(hi));
  return r;
}

#define PIN(v) asm volatile("" : "+v"(v))

// ASYNC x prefetch via volatile asm (r9-proven: loads genuinely decoupled).
#define GLOAD16(R0, R1, R2, R3, P)                                  \
  asm volatile("global_load_dwordx4 %0, %4, off\n\t"                \
               "global_load_dwordx4 %1, %4, off offset:16\n\t"      \
               "global_load_dwordx4 %2, %4, off offset:32\n\t"      \
               "global_load_dwordx4 %3, %4, off offset:48"          \
               : "=&v"(R0), "=&v"(R1), "=&v"(R2), "=&v"(R3)         \
               : "v"(P))

#define WAITX(N)                                                    \
  do {                                                              \
    asm volatile("s_waitcnt vmcnt(" #N ")" ::: "memory");           \
    __builtin_amdgcn_sched_barrier(0);                              \
  } while (0)

// Pack one f32 weight row (stride STR, N2 half2 pairs) into resident half2 VGPRs.
#define LOADW(DST, SRC, STR, N2)                                    \
  _Pragma("unroll") for (int k = 0; k < (N2); ++k) {                \
    DST[k][0] = (half_t)SRC[jr * (STR) + 2 * k];                    \
    DST[k][1] = (half_t)SRC[jr * (STR) + 2 * k + 1];                \
    PIN(DST[k]);                                                    \
  }

// REGISTER-ONLY h broadcast (replaces all LDS traffic):
//  1. quad_perm [1,0,3,2] (ctrl 0xB1): each lane gets its XOR-1 partner's h
//  2. v_cvt_pkrtz: even lane 2p now holds pack(h[2p], h[2p+1]) as 2xf16
//  3. 20 v_readlane from even lanes -> uniform SGPR pairs feeding dot2 directly
// Pure register ops: nothing the scheduler can sink; no LDS latency in chain.
#define BCAST(NH, PAIRS) do {                                       \
  int nb_ = __builtin_amdgcn_update_dpp(                            \
      0, __builtin_bit_cast(int, (NH)), 0xB1, 0xf, 0xf, false);     \
  h2 pk_ = __builtin_amdgcn_cvt_pkrtz((NH),                         \
      __builtin_bit_cast(float, nb_));                              \
  int pkb_ = __builtin_bit_cast(int, pk_);                          \
  _Pragma("unroll") for (int p = 0; p < H_ / 2; ++p)                \
    PAIRS[p] = __builtin_bit_cast(h2,                               \
        __builtin_amdgcn_readlane(pkb_, 2 * p));                    \
} while (0)

// 40-wide dot: 20 dot2 of uniform h pairs (SGPR) against resident weights.
#define HDS(PAIRS, W, A0, A1, A2, A3)                               \
  _Pragma("unroll") for (int p = 0; p < 5; ++p) {                   \
    A0 = dot2(PAIRS[4 * p + 0], (W)[4 * p + 0], A0);                \
    A1 = dot2(PAIRS[4 * p + 1], (W)[4 * p + 1], A1);                \
    A2 = dot2(PAIRS[4 * p + 2], (W)[4 * p + 2], A2);                \
    A3 = dot2(PAIRS[4 * p + 3], (W)[4 * p + 3], A3);                \
  }

// One RNN time step, zero LDS. hp0/hp1/hp2 are the 20-pair uniform h states.
// Order matters: L1 consumes NEW hp0 (bcast before L1) and OLD hp1 (bcast after).
#define STEP(XH) do {                                               \
  /* ---- layer 0 ---- */                                           \
  float a0 = bias0, a1 = 0.f, a2 = 0.f, a3 = 0.f;                   \
  a0 = dot2(XH[0], w0i[0], a0); a1 = dot2(XH[1], w0i[1], a1);       \
  a2 = dot2(XH[2], w0i[2], a2); a3 = dot2(XH[3], w0i[3], a3);       \
  a0 = dot2(XH[4], w0i[4], a0); a1 = dot2(XH[5], w0i[5], a1);       \
  a2 = dot2(XH[6], w0i[6], a2); a3 = dot2(XH[7], w0i[7], a3);       \
  HDS(hp0, w0h, a0, a1, a2, a3);  /* old h0 */                      \
  const float nh0 = fast_tanh((a0 + a1) + (a2 + a3));               \
  BCAST(nh0, hp0);                                                  \
  /* ---- layer 1 ---- */                                           \
  float b0 = bias1, b1 = 0.f, b2 = 0.f, b3 = 0.f;                   \
  HDS(hp0, w1i, b0, b1, b2, b3);  /* NEW h0 */                      \
  HDS(hp1, w1h, b0, b1, b2, b3);  /* old h1 */                      \
  const float nh1 = fast_tanh((b0 + b1) + (b2 + b3));               \
  BCAST(nh1, hp1);                                                  \
  /* ---- layer 2 ---- */                                           \
  float c0 = bias2, c1 = 0.f, c2 = 0.f, c3 = 0.f;                   \
  HDS(hp1, w2i, c0, c1, c2, c3);  /* NEW h1 */                      \
  HDS(hp2, w2h, c0, c1, c2, c3);  /* old h2 */                      \
  nh2v = fast_tanh((c0 + c1) + (c2 + c3));                          \
  BCAST(nh2v, hp2);                                                 \
} while (0)

// Use-site pack of one raw x buffer into h2[8].
#define PACKX(XH, R0, R1, R2, R3)                                   \
  do {                                                              \
    XH[0] = cvtpk_v(R0[0], R0[1]); XH[1] = cvtpk_v(R0[2], R0[3]);   \
    XH[2] = cvtpk_v(R1[0], R1[1]); XH[3] = cvtpk_v(R1[2], R1[3]);   \
    XH[4] = cvtpk_v(R2[0], R2[1]); XH[5] = cvtpk_v(R2[2], R2[3]);   \
    XH[6] = cvtpk_v(R3[0], R3[1]); XH[7] = cvtpk_v(R3[2], R3[3]);   \
  } while (0)

__global__ __launch_bounds__(64)
__attribute__((amdgpu_waves_per_eu(1, 1)))  // full 512-reg budget
void rnn3_fused(const float* __restrict__ x,
                const float* __restrict__ wih0, const float* __restrict__ whh0,
                const float* __restrict__ bih0, const float* __restrict__ bhh0,
                const float* __restrict__ wih1, const float* __restrict__ whh1,
                const float* __restrict__ b_ih1, const float* __restrict__ bhh1,
                const float* __restrict__ wih2, const float* __restrict__ whh2,
                const float* __restrict__ bih2, const float* __restrict__ bhh2,
                const float* __restrict__ fcw, const float* __restrict__ fcb,
                float* __restrict__ out) {
  const int b = blockIdx.x;
  const int j = threadIdx.x;               // lane = hidden unit (j < 40 real)
  const int jr = (j < H_) ? j : (H_ - 1);  // lanes 40..63 duplicate unit 39

  // ---- weights packed fp16: 108 resident VGPRs/lane ----
  h2 w0i[I_ / 2], w0h[H_ / 2], w1i[H_ / 2], w1h[H_ / 2], w2i[H_ / 2], w2h[H_ / 2];
  LOADW(w0i, wih0, I_, I_ / 2)
  LOADW(w0h, whh0, H_, H_ / 2)
  LOADW(w1i, wih1, H_, H_ / 2)
  LOADW(w1h, whh1, H_, H_ / 2)
  LOADW(w2i, wih2, H_, H_ / 2)
  LOADW(w2h, whh2, H_, H_ / 2)

  float bias0 = bih0[jr] + bhh0[jr];  PIN(bias0);
  float bias1 = b_ih1[jr] + bhh1[jr]; PIN(bias1);
  float bias2 = bih2[jr] + bhh2[jr];  PIN(bias2);

  // h state as 3x20 uniform fp16 pairs (SGPR-resident; h(0) = 0)
  h2 hp0[H_ / 2], hp1[H_ / 2], hp2[H_ / 2];
#pragma unroll
  for (int p = 0; p < H_ / 2; ++p) {
    hp0[p] = h2{(half_t)0.f, (half_t)0.f};
    hp1[p] = h2{(half_t)0.f, (half_t)0.f};
    hp2[p] = h2{(half_t)0.f, (half_t)0.f};
  }

  const float* __restrict__ xb = x + (size_t)b * (T_ * I_);

  // Two async 64B x buffers, distance-2 (r9 pipeline).
  f4 rA0, rA1, rA2, rA3, rB0, rB1, rB2, rB3;
  GLOAD16(rA0, rA1, rA2, rA3, xb + 0 * I_);   // t = 0
  GLOAD16(rB0, rB1, rB2, rB3, xb + 1 * I_);   // t = 1

  float nh2v = 0.f;
  h2 xh[8];

  for (int t = 0; t < T_; t += 2) {
    WAITX(4);                     // A ready (B still in flight)
    PACKX(xh, rA0, rA1, rA2, rA3);
    STEP(xh);
    { const float* pf = xb + (size_t)((t + 2 < T_) ? t + 2 : T_ - 1) * I_;
      GLOAD16(rA0, rA1, rA2, rA3, pf); }
    WAITX(4);                     // B ready (new A in flight)
    PACKX(xh, rB0, rB1, rB2, rB3);
    STEP(xh);
    { const float* pf = xb + (size_t)((t + 3 < T_) ? t + 3 : T_ - 1) * I_;
      GLOAD16(rB0, rB1, rB2, rB3, pf); }
  }

  // Drain all async loads before their destination registers are reused.
  asm volatile("s_waitcnt vmcnt(0)" ::: "memory");
  __builtin_amdgcn_sched_barrier(0);
  PIN(rA0); PIN(rA1); PIN(rA2); PIN(rA3);
  PIN(rB0); PIN(rB1); PIN(rB2); PIN(rB3);

  // ---- FC head: out[b] = sum_j fc_w[j]*h2[j] + fc_b ----
  const float fw = (j < H_) ? fcw[j] : 0.f;  // dup lanes (40..63) contribute 0
  float v = nh2v * fw;
#pragma unroll
  for (int off = 32; off > 0; off >>= 1) v += __shfl_down(v, off);
  if (j == 0) out[b] = v + fcb[0];
}

extern "C" void kernel_launch(void* const* d_in, const int* in_sizes, int n_in,
                              void* d_out, int out_size, void* d_ws, size_t ws_size,
                              hipStream_t stream) {
  (void)in_sizes; (void)n_in; (void)d_ws; (void)ws_size; (void)out_size;
  const float* x    = (const float*)d_in[0];
  const float* wih0 = (const float*)d_in[1];
  const float* whh0 = (const float*)d_in[2];
  const float* bih0 = (const float*)d_in[3];
  const float* bhh0 = (const float*)d_in[4];
  const float* wih1 = (const float*)d_in[5];
  const float* whh1 = (const float*)d_in[6];
  const float* bih1 = (const float*)d_in[7];
  const float* bhh1 = (const float*)d_in[8];
  const float* wih2 = (const float*)d_in[9];
  const float* whh2 = (const float*)d_in[10];
  const float* bih2 = (const float*)d_in[11];
  const float* bhh2 = (const float*)d_in[12];
  const float* fcw  = (const float*)d_in[13];
  const float* fcb  = (const float*)d_in[14];
  float* out = (float*)d_out;

  hipLaunchKernelGGL(rnn3_fused, dim3(B_), dim3(64), 0, stream,
                     x, wih0, whh0, bih0, bhh0,
                     wih1, whh1, bih1, bhh1,
                     wih2, whh2, bih2, bhh2,
                     fcw, fcb, out);
}

// Round 11
// 895.015 us; speedup vs baseline: 2.6232x; 1.0349x over previous
//
#include <hip/hip_runtime.h>
#include <cstddef>
#include <cstdint>

#define B_ 512
#define T_ 2048
#define I_ 16
#define H_ 40

typedef __fp16 half_t;  // matches __builtin_amdgcn_* vector element type exactly
typedef half_t h2 __attribute__((ext_vector_type(2)));
typedef float f4 __attribute__((ext_vector_type(4)));  // asm-constraint-compatible 128b reg quad

// tanh(x) = 1 - 2/(exp(2x)+1); exp(2x) = exp2(x * 2*log2(e)).
__device__ __forceinline__ float fast_tanh(float x) {
  float e = __builtin_amdgcn_exp2f(x * 2.8853900817779268f);
  return 1.0f - 2.0f * __builtin_amdgcn_rcpf(e + 1.0f);
}

// v_dot2_f32_f16: 2 fp16 MACs with f32 accumulate. One src may be SGPR-uniform.
__device__ __forceinline__ float dot2(h2 a, h2 b, float c) {
  return __builtin_amdgcn_fdot2(a, b, c, false);
}

// Use-site fp16 pack for x (volatile: ordered after the volatile WAITX; the
// compiler cannot hoist it back next to the load).
__device__ __forceinline__ h2 cvtpk_v(float lo, float hi) {
  h2 r;
  asm volatile("v_cvt_pkrtz_f16_f32 %0, %1, %2" : "=v"(r) : "v"(lo), "v"(hi));
  return r;
}

#define PIN(v) asm volatile("" : "+v"(v))

// ASYNC x prefetch via volatile asm with immediate offsets (one base pointer
// per 4-step group). Offsets are literal tokens.
#define GLOADQ(R0, R1, R2, R3, P, O0, O1, O2, O3)                   \
  asm volatile("global_load_dwordx4 %0, %4, off offset:" #O0 "\n\t" \
               "global_load_dwordx4 %1, %4, off offset:" #O1 "\n\t" \
               "global_load_dwordx4 %2, %4, off offset:" #O2 "\n\t" \
               "global_load_dwordx4 %3, %4, off offset:" #O3        \
               : "=&v"(R0), "=&v"(R1), "=&v"(R2), "=&v"(R3)         \
               : "v"(P))

// Counted wait, NO sched_barrier / memory clobber (r10 post-mortem: every
// consumer of the async regs is volatile asm, so volatile ordering suffices;
// the sched_barrier was fencing the whole scheduler twice per 2 steps).
#define WAITX(N) asm volatile("s_waitcnt vmcnt(" #N ")")

// Pack one f32 weight row (stride STR, N2 half2 pairs) into resident half2 VGPRs.
#define LOADW(DST, SRC, STR, N2)                                    \
  _Pragma("unroll") for (int k = 0; k < (N2); ++k) {                \
    DST[k][0] = (half_t)SRC[jr * (STR) + 2 * k];                    \
    DST[k][1] = (half_t)SRC[jr * (STR) + 2 * k + 1];                \
    PIN(DST[k]);                                                    \
  }

// REGISTER-ONLY h broadcast (r10-proven):
//  quad_perm [1,0,3,2] -> even lane 2p packs (h[2p],h[2p+1]) -> 20 readlanes
//  into uniform SGPR pairs feeding dot2 directly. No LDS in the chain.
#define BCAST(NH, PAIRS) do {                                       \
  int nb_ = __builtin_amdgcn_update_dpp(                            \
      0, __builtin_bit_cast(int, (NH)), 0xB1, 0xf, 0xf, false);     \
  h2 pk_ = __builtin_amdgcn_cvt_pkrtz((NH),                         \
      __builtin_bit_cast(float, nb_));                              \
  int pkb_ = __builtin_bit_cast(int, pk_);                          \
  _Pragma("unroll") for (int p = 0; p < H_ / 2; ++p)                \
    PAIRS[p] = __builtin_bit_cast(h2,                               \
        __builtin_amdgcn_readlane(pkb_, 2 * p));                    \
} while (0)

// 40-wide dot: 20 dot2 of uniform h pairs (SGPR) against resident weights.
#define HDS(PAIRS, W, A0, A1, A2, A3)                               \
  _Pragma("unroll") for (int p = 0; p < 5; ++p) {                   \
    A0 = dot2(PAIRS[4 * p + 0], (W)[4 * p + 0], A0);                \
    A1 = dot2(PAIRS[4 * p + 1], (W)[4 * p + 1], A1);                \
    A2 = dot2(PAIRS[4 * p + 2], (W)[4 * p + 2], A2);                \
    A3 = dot2(PAIRS[4 * p + 3], (W)[4 * p + 3], A3);                \
  }

// One RNN time step, zero LDS (r10 structure).
#define STEP(XH) do {                                               \
  /* ---- layer 0 ---- */                                           \
  float a0 = bias0, a1 = 0.f, a2 = 0.f, a3 = 0.f;                   \
  a0 = dot2(XH[0], w0i[0], a0); a1 = dot2(XH[1], w0i[1], a1);       \
  a2 = dot2(XH[2], w0i[2], a2); a3 = dot2(XH[3], w0i[3], a3);       \
  a0 = dot2(XH[4], w0i[4], a0); a1 = dot2(XH[5], w0i[5], a1);       \
  a2 = dot2(XH[6], w0i[6], a2); a3 = dot2(XH[7], w0i[7], a3);       \
  HDS(hp0, w0h, a0, a1, a2, a3);  /* old h0 */                      \
  const float nh0 = fast_tanh((a0 + a1) + (a2 + a3));               \
  BCAST(nh0, hp0);                                                  \
  /* ---- layer 1 ---- */                                           \
  float b0 = bias1, b1 = 0.f, b2 = 0.f, b3 = 0.f;                   \
  HDS(hp0, w1i, b0, b1, b2, b3);  /* NEW h0 */                      \
  HDS(hp1, w1h, b0, b1, b2, b3);  /* old h1 */                      \
  const float nh1 = fast_tanh((b0 + b1) + (b2 + b3));               \
  BCAST(nh1, hp1);                                                  \
  /* ---- layer 2 ---- */                                           \
  float c0 = bias2, c1 = 0.f, c2 = 0.f, c3 = 0.f;                   \
  HDS(hp1, w2i, c0, c1, c2, c3);  /* NEW h1 */                      \
  HDS(hp2, w2h, c0, c1, c2, c3);  /* old h2 */                      \
  nh2v = fast_tanh((c0 + c1) + (c2 + c3));                          \
  BCAST(nh2v, hp2);                                                 \
} while (0)

// Use-site pack of one raw x buffer into h2[8].
#define PACKX(XH, R0, R1, R2, R3)                                   \
  do {                                                              \
    XH[0] = cvtpk_v(R0[0], R0[1]); XH[1] = cvtpk_v(R0[2], R0[3]);   \
    XH[2] = cvtpk_v(R1[0], R1[1]); XH[3] = cvtpk_v(R1[2], R1[3]);   \
    XH[4] = cvtpk_v(R2[0], R2[1]); XH[5] = cvtpk_v(R2[2], R2[3]);   \
    XH[6] = cvtpk_v(R3[0], R3[1]); XH[7] = cvtpk_v(R3[2], R3[3]);   \
  } while (0)

__global__ __launch_bounds__(64)
__attribute__((amdgpu_waves_per_eu(1, 1)))  // full 512-reg budget
void rnn3_fused(const float* __restrict__ x,
                const float* __restrict__ wih0, const float* __restrict__ whh0,
                const float* __restrict__ bih0, const float* __restrict__ bhh0,
                const float* __restrict__ wih1, const float* __restrict__ whh1,
                const float* __restrict__ b_ih1, const float* __restrict__ bhh1,
                const float* __restrict__ wih2, const float* __restrict__ whh2,
                const float* __restrict__ bih2, const float* __restrict__ bhh2,
                const float* __restrict__ fcw, const float* __restrict__ fcb,
                float* __restrict__ out) {
  const int b = blockIdx.x;
  const int j = threadIdx.x;               // lane = hidden unit (j < 40 real)
  const int jr = (j < H_) ? j : (H_ - 1);  // lanes 40..63 duplicate unit 39

  // ---- weights packed fp16: 108 resident VGPRs/lane ----
  h2 w0i[I_ / 2], w0h[H_ / 2], w1i[H_ / 2], w1h[H_ / 2], w2i[H_ / 2], w2h[H_ / 2];
  LOADW(w0i, wih0, I_, I_ / 2)
  LOADW(w0h, whh0, H_, H_ / 2)
  LOADW(w1i, wih1, H_, H_ / 2)
  LOADW(w1h, whh1, H_, H_ / 2)
  LOADW(w2i, wih2, H_, H_ / 2)
  LOADW(w2h, whh2, H_, H_ / 2)

  float bias0 = bih0[jr] + bhh0[jr];  PIN(bias0);
  float bias1 = b_ih1[jr] + bhh1[jr]; PIN(bias1);
  float bias2 = bih2[jr] + bhh2[jr];  PIN(bias2);

  // h state as 3x20 uniform fp16 pairs (SGPR-resident; h(0) = 0)
  h2 hp0[H_ / 2], hp1[H_ / 2], hp2[H_ / 2];
#pragma unroll
  for (int p = 0; p < H_ / 2; ++p) {
    hp0[p] = h2{(half_t)0.f, (half_t)0.f};
    hp1[p] = h2{(half_t)0.f, (half_t)0.f};
    hp2[p] = h2{(half_t)0.f, (half_t)0.f};
  }

  const float* __restrict__ xb = x + (size_t)b * (T_ * I_);

  // Four async 64B x buffers = one 4-step group in flight (16 loads).
  f4 rA0, rA1, rA2, rA3, rB0, rB1, rB2, rB3;
  f4 rC0, rC1, rC2, rC3, rD0, rD1, rD2, rD3;
  GLOADQ(rA0, rA1, rA2, rA3, xb,   0,  16,  32,  48);   // t = 0
  GLOADQ(rB0, rB1, rB2, rB3, xb,  64,  80,  96, 112);   // t = 1
  GLOADQ(rC0, rC1, rC2, rC3, xb, 128, 144, 160, 176);   // t = 2
  GLOADQ(rD0, rD1, rD2, rD3, xb, 192, 208, 224, 240);   // t = 3

  float nh2v = 0.f;
  h2 xh[8];

  for (int t = 0; t < T_; t += 4) {
    // prefetch base for the next group (clamped: last group re-reads t=2044..2047)
    const float* pf = xb + (size_t)((t + 4 < T_) ? (t + 4) : (T_ - 4)) * I_;
    WAITX(12);                    // A ready (B,C,D + any newer in flight)
    PACKX(xh, rA0, rA1, rA2, rA3);
    STEP(xh);
    GLOADQ(rA0, rA1, rA2, rA3, pf,   0,  16,  32,  48);
    WAITX(12);                    // B ready
    PACKX(xh, rB0, rB1, rB2, rB3);
    STEP(xh);
    GLOADQ(rB0, rB1, rB2, rB3, pf,  64,  80,  96, 112);
    WAITX(12);                    // C ready
    PACKX(xh, rC0, rC1, rC2, rC3);
    STEP(xh);
    GLOADQ(rC0, rC1, rC2, rC3, pf, 128, 144, 160, 176);
    WAITX(12);                    // D ready
    PACKX(xh, rD0, rD1, rD2, rD3);
    STEP(xh);
    GLOADQ(rD0, rD1, rD2, rD3, pf, 192, 208, 224, 240);
  }

  // Drain all async loads before their destination registers are reused.
  asm volatile("s_waitcnt vmcnt(0)");
  PIN(rA0); PIN(rA1); PIN(rA2); PIN(rA3);
  PIN(rB0); PIN(rB1); PIN(rB2); PIN(rB3);
  PIN(rC0); PIN(rC1); PIN(rC2); PIN(rC3);
  PIN(rD0); PIN(rD1); PIN(rD2); PIN(rD3);

  // ---- FC head: out[b] = sum_j fc_w[j]*h2[j] + fc_b ----
  const float fw = (j < H_) ? fcw[j] : 0.f;  // dup lanes (40..63) contribute 0
  float v = nh2v * fw;
#pragma unroll
  for (int off = 32; off > 0; off >>= 1) v += __shfl_down(v, off);
  if (j == 0) out[b] = v + fcb[0];
}

extern "C" void kernel_launch(void* const* d_in, const int* in_sizes, int n_in,
                              void* d_out, int out_size, void* d_ws, size_t ws_size,
                              hipStream_t stream) {
  (void)in_sizes; (void)n_in; (void)d_ws; (void)ws_size; (void)out_size;
  const float* x    = (const float*)d_in[0];
  const float* wih0 = (const float*)d_in[1];
  const float* whh0 = (const float*)d_in[2];
  const float* bih0 = (const float*)d_in[3];
  const float* bhh0 = (const float*)d_in[4];
  const float* wih1 = (const float*)d_in[5];
  const float* whh1 = (const float*)d_in[6];
  const float* bih1 = (const float*)d_in[7];
  const float* bhh1 = (const float*)d_in[8];
  const float* wih2 = (const float*)d_in[9];
  const float* whh2 = (const float*)d_in[10];
  const float* bih2 = (const float*)d_in[11];
  const float* bhh2 = (const float*)d_in[12];
  const float* fcw  = (const float*)d_in[13];
  const float* fcb  = (const float*)d_in[14];
  float* out = (float*)d_out;

  hipLaunchKernelGGL(rnn3_fused, dim3(B_), dim3(64), 0, stream,
                     x, wih0, whh0, bih0, bhh0,
                     wih1, whh1, bih1, bhh1,
                     wih2, whh2, bih2, bhh2,
                     fcw, fcb, out);
}